// Round 1
// baseline (1920.882 us; speedup 1.0000x reference)
//
#include <hip/hip_runtime.h>

#define BATCH 256
#define IMGD 768
#define TXTD 512
#define HID 312
#define KK 16
#define CH 78
#define WP 80
#define PITCH 17

// out layout (float32, flat, return order):
//   adj_lin  [256,312] @ 0
//   noun_lin [256,200] @ 79872
//   adj_cls  [256,312] @ 131072
//   noun_cls [256,200] @ 210944

__global__ __launch_bounds__(256, 2)
void heads_kernel(const float* __restrict__ img,
                  const float* __restrict__ adj_txt, const float* __restrict__ noun_txt,
                  const float* __restrict__ adj_linW, const float* __restrict__ adj_linb,
                  const float* __restrict__ adj_W1, const float* __restrict__ adj_b1,
                  const float* __restrict__ adj_g, const float* __restrict__ adj_bt,
                  const float* __restrict__ adj_W2, const float* __restrict__ adj_b2,
                  const float* __restrict__ noun_linW, const float* __restrict__ noun_linb,
                  const float* __restrict__ noun_W1, const float* __restrict__ noun_b1,
                  const float* __restrict__ noun_g, const float* __restrict__ noun_bt,
                  const float* __restrict__ noun_W2, const float* __restrict__ noun_b2,
                  float* __restrict__ out)
{
    __shared__ __align__(16) float img_s[BATCH * PITCH]; // 17408 B
    __shared__ __align__(16) float w_s[KK * WP];         // 5120 B
    __shared__ float txt_s[TXTD];
    __shared__ float tv_s[320];
    __shared__ float linw_s[IMGD];
    __shared__ float g_s[HID], bt_s[HID], w2_s[HID];
    __shared__ float cls_s[4 * BATCH];
    __shared__ float red_s[4];

    const int k = blockIdx.x;
    const bool adj = (k < 312);
    const int kloc = adj ? k : (k - 312);
    const int KD = adj ? 312 : 200;
    const float* txt  = (adj ? adj_txt  : noun_txt)  + (size_t)kloc * TXTD;
    const float* linW = (adj ? adj_linW : noun_linW) + (size_t)kloc * (IMGD + TXTD);
    const float* linb = adj ? adj_linb : noun_linb;
    const float* W1   = (adj ? adj_W1 : noun_W1) + (size_t)kloc * (IMGD + TXTD) * HID;
    const float* b1   = (adj ? adj_b1 : noun_b1) + (size_t)kloc * HID;
    const float* gam  = (adj ? adj_g  : noun_g ) + (size_t)kloc * HID;
    const float* bet  = (adj ? adj_bt : noun_bt) + (size_t)kloc * HID;
    const float* W2   = (adj ? adj_W2 : noun_W2) + (size_t)kloc * HID;
    const float* b2   = adj ? adj_b2 : noun_b2;
    float* lin_out = out + (adj ? 0 : 79872);
    float* cls_out = out + (adj ? 131072 : 210944);

    const int tid = threadIdx.x;
    const int lane = tid & 63;
    const int q = tid >> 6;          // wave id: owns cols [q*20, q*20+20) of each chunk
    const int colbase = q * 20;

    // ---- phase 1: stage head-local small tensors ----
    txt_s[tid] = txt[tid];
    txt_s[tid + 256] = txt[tid + 256];
    for (int h = tid; h < HID; h += 256) {
        g_s[h] = gam[h]; bt_s[h] = bet[h]; w2_s[h] = W2[h];
    }
    for (int d = tid; d < IMGD; d += 256) linw_s[d] = linW[d];
    __syncthreads();

    // tvec[h] = b1[h] + sum_d txt[d] * W1[768+d][h]   (coalesced over h)
    for (int h = tid; h < 320; h += 256) {
        float tv = 0.f;
        if (h < HID) {
            tv = b1[h];
            #pragma unroll 8
            for (int d = 0; d < TXTD; ++d)
                tv += txt_s[d] * W1[(size_t)(IMGD + d) * HID + h];
        }
        tv_s[h] = tv;
    }

    // lin text part (scalar per head)
    float p = txt_s[tid] * linW[IMGD + tid] + txt_s[tid + 256] * linW[IMGD + tid + 256];
    #pragma unroll
    for (int off = 32; off > 0; off >>= 1) p += __shfl_xor(p, off, 64);
    if (lane == 0) red_s[q] = p;
    __syncthreads();
    const float lin_txt = red_s[0] + red_s[1] + red_s[2] + red_s[3];

    // ---- main: 4 column chunks of 78, fused GEMM + ReLU + BN + W2 ----
    float lin_acc[4] = {0.f, 0.f, 0.f, 0.f};
    float cls_acc[4] = {0.f, 0.f, 0.f, 0.f};

    for (int c0 = 0; c0 < HID; c0 += CH) {
        float acc[4][20];
        #pragma unroll
        for (int i = 0; i < 4; ++i)
            #pragma unroll
            for (int n = 0; n < 20; ++n) acc[i][n] = 0.f;

        for (int kk0 = 0; kk0 < IMGD; kk0 += KK) {
            __syncthreads();   // previous tile fully consumed
            // stage img slab [256][16] -> pitch-17 LDS (conflict-free col reads)
            {
                const int c = tid & 15, r0 = tid >> 4;
                #pragma unroll
                for (int l = 0; l < 16; ++l) {
                    const int r = r0 + 16 * l;
                    img_s[r * PITCH + c] = img[(size_t)r * IMGD + kk0 + c];
                }
            }
            // stage W1 slab [16][78] (pad cols 78,79 with 0)
            #pragma unroll
            for (int l = 0; l < 5; ++l) {
                const int e = tid + 256 * l;
                const int j = e / WP, cc = e - j * WP;
                w_s[e] = (cc < CH) ? W1[(size_t)(kk0 + j) * HID + c0 + cc] : 0.f;
            }
            __syncthreads();

            #pragma unroll 4
            for (int j = 0; j < KK; ++j) {
                const float a0 = img_s[(lane      ) * PITCH + j];
                const float a1 = img_s[(lane +  64) * PITCH + j];
                const float a2 = img_s[(lane + 128) * PITCH + j];
                const float a3 = img_s[(lane + 192) * PITCH + j];
                const float4* wr4 = reinterpret_cast<const float4*>(&w_s[j * WP + colbase]);
                #pragma unroll
                for (int n4 = 0; n4 < 5; ++n4) {
                    const float4 wv = wr4[n4];
                    acc[0][4*n4+0] += a0 * wv.x; acc[0][4*n4+1] += a0 * wv.y;
                    acc[0][4*n4+2] += a0 * wv.z; acc[0][4*n4+3] += a0 * wv.w;
                    acc[1][4*n4+0] += a1 * wv.x; acc[1][4*n4+1] += a1 * wv.y;
                    acc[1][4*n4+2] += a1 * wv.z; acc[1][4*n4+3] += a1 * wv.w;
                    acc[2][4*n4+0] += a2 * wv.x; acc[2][4*n4+1] += a2 * wv.y;
                    acc[2][4*n4+2] += a2 * wv.z; acc[2][4*n4+3] += a2 * wv.w;
                    acc[3][4*n4+0] += a3 * wv.x; acc[3][4*n4+1] += a3 * wv.y;
                    acc[3][4*n4+2] += a3 * wv.z; acc[3][4*n4+3] += a3 * wv.w;
                }
                if (c0 == 0 && q == 0) {  // wave-uniform branch: lin rides along once
                    const float lw = linw_s[kk0 + j];
                    lin_acc[0] += a0 * lw; lin_acc[1] += a1 * lw;
                    lin_acc[2] += a2 * lw; lin_acc[3] += a3 * lw;
                }
            }
        }

        // fused epilogue: ReLU -> batch stats (intra-wave) -> BN -> *W2
        #pragma unroll
        for (int n = 0; n < 20; ++n) {
            const int gcol = c0 + colbase + n;        // <= 313 < 320 (tv_s padded)
            const float tv = tv_s[gcol];
            const float h0 = fmaxf(acc[0][n] + tv, 0.f);
            const float h1 = fmaxf(acc[1][n] + tv, 0.f);
            const float h2 = fmaxf(acc[2][n] + tv, 0.f);
            const float h3 = fmaxf(acc[3][n] + tv, 0.f);
            float s  = h0 + h1 + h2 + h3;
            float ss = h0*h0 + h1*h1 + h2*h2 + h3*h3;
            #pragma unroll
            for (int off = 32; off > 0; off >>= 1) {
                s  += __shfl_xor(s,  off, 64);
                ss += __shfl_xor(ss, off, 64);
            }
            const float mean = s * (1.f / 256.f);
            const float var  = ss * (1.f / 256.f) - mean * mean;
            const float rstd = rsqrtf(var + 1e-5f);
            const bool valid = (colbase + n) < CH;
            const int gc = valid ? gcol : 0;
            const float w2v = valid ? w2_s[gc] : 0.f;
            const float a  = rstd * g_s[gc];
            const float bq = bt_s[gc] - mean * a;     // norm = h*a + bq
            cls_acc[0] += (h0 * a + bq) * w2v;
            cls_acc[1] += (h1 * a + bq) * w2v;
            cls_acc[2] += (h2 * a + bq) * w2v;
            cls_acc[3] += (h3 * a + bq) * w2v;
        }
    }

    // cls: cross-wave reduce via LDS
    #pragma unroll
    for (int i = 0; i < 4; ++i) cls_s[q * BATCH + lane + 64 * i] = cls_acc[i];
    __syncthreads();
    {
        const int b = tid;
        const float v = cls_s[b] + cls_s[BATCH + b] + cls_s[2 * BATCH + b]
                      + cls_s[3 * BATCH + b] + b2[kloc];
        cls_out[(size_t)b * KD + kloc] = v;
    }
    if (q == 0) {
        const float lb = linb[kloc] + lin_txt;
        #pragma unroll
        for (int i = 0; i < 4; ++i) {
            const int r = lane + 64 * i;
            lin_out[(size_t)r * KD + kloc] = lin_acc[i] + lb;
        }
    }
}

extern "C" void kernel_launch(void* const* d_in, const int* in_sizes, int n_in,
                              void* d_out, int out_size, void* d_ws, size_t ws_size,
                              hipStream_t stream) {
    const float* img       = (const float*)d_in[0];
    const float* adj_txt   = (const float*)d_in[1];
    const float* noun_txt  = (const float*)d_in[2];
    const float* adj_linW  = (const float*)d_in[3];
    const float* adj_linb  = (const float*)d_in[4];
    const float* adj_W1    = (const float*)d_in[5];
    const float* adj_b1    = (const float*)d_in[6];
    const float* adj_g     = (const float*)d_in[7];
    const float* adj_bt    = (const float*)d_in[8];
    const float* adj_W2    = (const float*)d_in[9];
    const float* adj_b2    = (const float*)d_in[10];
    const float* noun_linW = (const float*)d_in[11];
    const float* noun_linb = (const float*)d_in[12];
    const float* noun_W1   = (const float*)d_in[13];
    const float* noun_b1   = (const float*)d_in[14];
    const float* noun_g    = (const float*)d_in[15];
    const float* noun_bt   = (const float*)d_in[16];
    const float* noun_W2   = (const float*)d_in[17];
    const float* noun_b2   = (const float*)d_in[18];
    float* out = (float*)d_out;

    hipLaunchKernelGGL(heads_kernel, dim3(512), dim3(256), 0, stream,
                       img, adj_txt, noun_txt,
                       adj_linW, adj_linb, adj_W1, adj_b1, adj_g, adj_bt, adj_W2, adj_b2,
                       noun_linW, noun_linb, noun_W1, noun_b1, noun_g, noun_bt, noun_W2, noun_b2,
                       out);
}